// Round 3
// baseline (1441.559 us; speedup 1.0000x reference)
//
#include <hip/hip_runtime.h>

#define N_USERS 100000
#define N_ITEMS 50000
#define N_NODES 150000
#define DIM 64
#define NNZ 4000000
#define BATCH 4096
#define BSHIFT 7                                    // 128 nodes per bucket
#define NBUCK ((N_NODES + (1 << BSHIFT) - 1) >> BSHIFT)   // 1172

// ---------------- init: concat user/item embeddings into X and ACC ----------
__global__ void init_k(const float4* __restrict__ ue, const float4* __restrict__ ie,
                       float4* __restrict__ X, float4* __restrict__ ACC) {
    int i = blockIdx.x * blockDim.x + threadIdx.x;
    const int total  = N_NODES * DIM / 4;
    const int ubound = N_USERS * DIM / 4;
    if (i < total) {
        float4 v = (i < ubound) ? ue[i] : ie[i - ubound];
        X[i]   = v;
        ACC[i] = v;
    }
}

// ---------------- CSR build --------------------------------------------------
__global__ void hist_k(const int* __restrict__ dst, int* __restrict__ cnt) {
    int e = blockIdx.x * blockDim.x + threadIdx.x;
    if (e < NNZ) atomicAdd(&cnt[dst[e]], 1);
}

__global__ void scan1_k(const int* __restrict__ cnt, int* __restrict__ row,
                        int* __restrict__ bsum) {
    __shared__ int sh[256];
    int tid  = threadIdx.x;
    int base = blockIdx.x * 1024 + tid * 4;
    int v0 = (base + 0 < N_NODES) ? cnt[base + 0] : 0;
    int v1 = (base + 1 < N_NODES) ? cnt[base + 1] : 0;
    int v2 = (base + 2 < N_NODES) ? cnt[base + 2] : 0;
    int v3 = (base + 3 < N_NODES) ? cnt[base + 3] : 0;
    int tsum = v0 + v1 + v2 + v3;
    sh[tid] = tsum;
    __syncthreads();
    for (int off = 1; off < 256; off <<= 1) {
        int t = (tid >= off) ? sh[tid - off] : 0;
        __syncthreads();
        sh[tid] += t;
        __syncthreads();
    }
    if (tid == 255) bsum[blockIdx.x] = sh[255];
    int excl = sh[tid] - tsum;
    if (base + 0 < N_NODES) row[base + 0] = excl;           excl += v0;
    if (base + 1 < N_NODES) row[base + 1] = excl;           excl += v1;
    if (base + 2 < N_NODES) row[base + 2] = excl;           excl += v2;
    if (base + 3 < N_NODES) row[base + 3] = excl;
}

__global__ void scan2_k(int* __restrict__ bsum, int nb) {
    __shared__ int sh[256];
    int tid = threadIdx.x;
    int v = (tid < nb) ? bsum[tid] : 0;
    sh[tid] = v;
    __syncthreads();
    for (int off = 1; off < 256; off <<= 1) {
        int t = (tid >= off) ? sh[tid - off] : 0;
        __syncthreads();
        sh[tid] += t;
        __syncthreads();
    }
    if (tid < nb) bsum[tid] = sh[tid] - v;
}

__global__ void scan3_k(int* __restrict__ row, const int* __restrict__ bsum) {
    int i = blockIdx.x * blockDim.x + threadIdx.x;
    if (i < N_NODES) row[i] += bsum[i >> 10];
    if (i == 0) row[N_NODES] = NNZ;
}

// pass B: bucket edges by dst>>BSHIFT; ticket-sequential SoA writes
__global__ void bucket_k(const int* __restrict__ src, const int* __restrict__ dst,
                         const float* __restrict__ val, const int* __restrict__ row,
                         int* __restrict__ boff,
                         int* __restrict__ bsrc, float* __restrict__ bval,
                         int* __restrict__ bdst) {
    int e = blockIdx.x * blockDim.x + threadIdx.x;
    if (e >= NNZ) return;
    int d = dst[e];
    int p = row[d & ~((1 << BSHIFT) - 1)] + atomicAdd(&boff[d >> BSHIFT], 1);
    bsrc[p] = src[e];
    bval[p] = val[e];
    bdst[p] = d;
}

// pass C: exact CSR placement; writes confined to L2-resident bucket windows
__global__ void place2_k(const int* __restrict__ bsrc, const float* __restrict__ bval,
                         const int* __restrict__ bdst, const int* __restrict__ row,
                         int* __restrict__ off, int2* __restrict__ sorted) {
    int i = blockIdx.x * blockDim.x + threadIdx.x;
    if (i >= NNZ) return;
    int d = bdst[i];
    int pos = row[d] + atomicAdd(&off[d], 1);
    sorted[pos] = make_int2(bsrc[i], __float_as_int(bval[i]));
}

// ---------------- gather SpMM: Y[d] = sum val*X[src]; ACC += Y ---------------
__global__ void gather_k(const int* __restrict__ row, const int2* __restrict__ se,
                         const float* __restrict__ X, float* __restrict__ Y,
                         float* __restrict__ ACC) {
    int wid  = (blockIdx.x * blockDim.x + threadIdx.x) >> 6;   // node
    int lane = threadIdx.x & 63;                               // dim
    if (wid >= N_NODES) return;
    int beg = row[wid], end = row[wid + 1];
    float acc = 0.f;
    for (int base = beg; base < end; base += 64) {
        int rem = end - base;
        int n = rem < 64 ? rem : 64;
        int2 ev = make_int2(0, 0);
        if (lane < n) ev = se[base + lane];
        int n4 = (n + 3) & ~3;
        for (int j = 0; j < n4; j += 4) {
            int   s0 = __shfl(ev.x, j + 0, 64);
            int   s1 = __shfl(ev.x, j + 1, 64);
            int   s2 = __shfl(ev.x, j + 2, 64);
            int   s3 = __shfl(ev.x, j + 3, 64);
            float v0 = __int_as_float(__shfl(ev.y, j + 0, 64));
            float v1 = __int_as_float(__shfl(ev.y, j + 1, 64));
            float v2 = __int_as_float(__shfl(ev.y, j + 2, 64));
            float v3 = __int_as_float(__shfl(ev.y, j + 3, 64));
            float x0 = X[(s0 << 6) + lane];   // zero-padded lanes: v=0, s=0 (safe)
            float x1 = X[(s1 << 6) + lane];
            float x2 = X[(s2 << 6) + lane];
            float x3 = X[(s3 << 6) + lane];
            acc += v0 * x0;
            acc += v1 * x1;
            acc += v2 * x2;
            acc += v3 * x3;
        }
    }
    int o = (wid << 6) + lane;
    Y[o]   = acc;
    ACC[o] += acc;
}

// ---------------- final: gather rows, dot, sigmoid ---------------------------
__global__ void final_k(const int* __restrict__ users, const int* __restrict__ items,
                        const float* __restrict__ ACC, float* __restrict__ out) {
    int b    = blockIdx.x * (blockDim.x / 64) + (threadIdx.x / 64);
    int lane = threadIdx.x & 63;
    if (b >= BATCH) return;
    int ur = users[b];
    int ir = N_USERS + items[b];
    float u  = ACC[ur * 64 + lane];
    float it = ACC[ir * 64 + lane];
    float p  = u * it * (1.0f / 16.0f);
    #pragma unroll
    for (int off = 32; off; off >>= 1) p += __shfl_down(p, off, 64);
    if (lane == 0) out[b] = 1.0f / (1.0f + __expf(-p));
}

extern "C" void kernel_launch(void* const* d_in, const int* in_sizes, int n_in,
                              void* d_out, int out_size, void* d_ws, size_t ws_size,
                              hipStream_t stream) {
    const int*   users = (const int*)  d_in[0];
    const int*   items = (const int*)  d_in[1];
    const int*   esrc  = (const int*)  d_in[2];
    const int*   edst  = (const int*)  d_in[3];
    const float* eval  = (const float*)d_in[4];
    const float* uemb  = (const float*)d_in[5];
    const float* iemb  = (const float*)d_in[6];
    float*       out   = (float*)      d_out;

    const size_t EMB = (size_t)N_NODES * DIM * sizeof(float);      // 38.4 MB
    char* ws = (char*)d_ws;
    float* X      = (float*)(ws);
    float* Y      = (float*)(ws + EMB);
    float* ACC    = (float*)(ws + 2 * EMB);
    int2*  sorted = (int2*) (ws + 3 * EMB);                        // 32 MB
    char*  ws2    = ws + 3 * EMB + (size_t)NNZ * sizeof(int2);
    int*   row    = (int*)(ws2);                                   // N_NODES+1
    int*   cnt    = (int*)(ws2 + ((N_NODES + 2) * 4 + 255) / 256 * 256);
    int*   bsum   = (int*)((char*)cnt + ((size_t)N_NODES * 4 + 255) / 256 * 256);
    int*   boff   = (int*)((char*)bsum + 1024);
    // bucket SoA aliases Y/ACC (dead before init_k runs)
    int*   bsrc   = (int*)(ws + EMB);
    float* bval   = (float*)(ws + EMB + (size_t)NNZ * 4);
    int*   bdst   = (int*)(ws + EMB + (size_t)NNZ * 8);

    // ---- CSR build (by destination) ----
    hipMemsetAsync(cnt, 0, (size_t)N_NODES * 4, stream);
    hist_k<<<(NNZ + 255) / 256, 256, 0, stream>>>(edst, cnt);
    const int NB = (N_NODES + 1023) / 1024;                        // 147
    scan1_k<<<NB, 256, 0, stream>>>(cnt, row, bsum);
    scan2_k<<<1, 256, 0, stream>>>(bsum, NB);
    scan3_k<<<(N_NODES + 255) / 256, 256, 0, stream>>>(row, bsum);
    hipMemsetAsync(boff, 0, (size_t)NBUCK * 4, stream);
    bucket_k<<<(NNZ + 255) / 256, 256, 0, stream>>>(esrc, edst, eval, row, boff,
                                                    bsrc, bval, bdst);
    hipMemsetAsync(cnt, 0, (size_t)N_NODES * 4, stream);
    place2_k<<<(NNZ + 255) / 256, 256, 0, stream>>>(bsrc, bval, bdst, row, cnt, sorted);

    // ---- init AFTER bucket arrays are dead (they alias Y/ACC) ----
    const int totv = N_NODES * DIM / 4;
    init_k<<<(totv + 255) / 256, 256, 0, stream>>>(
        (const float4*)uemb, (const float4*)iemb, (float4*)X, (float4*)ACC);

    // ---- 3 gather layers, ACC fused ----
    const int gthreads = N_NODES * 64;
    for (int l = 0; l < 3; ++l) {
        gather_k<<<(gthreads + 255) / 256, 256, 0, stream>>>(row, sorted, X, Y, ACC);
        float* tmp = X; X = Y; Y = tmp;
    }

    final_k<<<(BATCH * 64 + 255) / 256, 256, 0, stream>>>(users, items, ACC, out);
}

// Round 4
// 683.143 us; speedup vs baseline: 2.1102x; 2.1102x over previous
//
#include <hip/hip_runtime.h>

#define N_USERS 100000
#define N_ITEMS 50000
#define N_NODES 150000
#define DIM 64
#define NNZ 4000000
#define BATCH 4096

// ---------------- init: concat user/item embeddings into X and ACC ----------
__global__ void init_k(const float4* __restrict__ ue, const float4* __restrict__ ie,
                       float4* __restrict__ X, float4* __restrict__ ACC) {
    int i = blockIdx.x * blockDim.x + threadIdx.x;
    const int total  = N_NODES * DIM / 4;
    const int ubound = N_USERS * DIM / 4;
    if (i < total) {
        float4 v = (i < ubound) ? ue[i] : ie[i - ubound];
        X[i]   = v;
        ACC[i] = v;
    }
}

// ---------------- CSR build --------------------------------------------------
// rank_k: histogram AND per-edge rank in one pass (atomic return value)
__global__ void rank_k(const int* __restrict__ dst, int* __restrict__ cnt,
                       int* __restrict__ rank) {
    int e = blockIdx.x * blockDim.x + threadIdx.x;
    if (e < NNZ) rank[e] = atomicAdd(&cnt[dst[e]], 1);
}

__global__ void scan1_k(const int* __restrict__ cnt, int* __restrict__ row,
                        int* __restrict__ bsum) {
    __shared__ int sh[256];
    int tid  = threadIdx.x;
    int base = blockIdx.x * 1024 + tid * 4;
    int v0 = (base + 0 < N_NODES) ? cnt[base + 0] : 0;
    int v1 = (base + 1 < N_NODES) ? cnt[base + 1] : 0;
    int v2 = (base + 2 < N_NODES) ? cnt[base + 2] : 0;
    int v3 = (base + 3 < N_NODES) ? cnt[base + 3] : 0;
    int tsum = v0 + v1 + v2 + v3;
    sh[tid] = tsum;
    __syncthreads();
    for (int off = 1; off < 256; off <<= 1) {
        int t = (tid >= off) ? sh[tid - off] : 0;
        __syncthreads();
        sh[tid] += t;
        __syncthreads();
    }
    if (tid == 255) bsum[blockIdx.x] = sh[255];
    int excl = sh[tid] - tsum;
    if (base + 0 < N_NODES) row[base + 0] = excl;           excl += v0;
    if (base + 1 < N_NODES) row[base + 1] = excl;           excl += v1;
    if (base + 2 < N_NODES) row[base + 2] = excl;           excl += v2;
    if (base + 3 < N_NODES) row[base + 3] = excl;
}

__global__ void scan2_k(int* __restrict__ bsum, int nb) {
    __shared__ int sh[256];
    int tid = threadIdx.x;
    int v = (tid < nb) ? bsum[tid] : 0;
    sh[tid] = v;
    __syncthreads();
    for (int off = 1; off < 256; off <<= 1) {
        int t = (tid >= off) ? sh[tid - off] : 0;
        __syncthreads();
        sh[tid] += t;
        __syncthreads();
    }
    if (tid < nb) bsum[tid] = sh[tid] - v;
}

__global__ void scan3_k(int* __restrict__ row, const int* __restrict__ bsum) {
    int i = blockIdx.x * blockDim.x + threadIdx.x;
    if (i < N_NODES) row[i] += bsum[i >> 10];
    if (i == 0) row[N_NODES] = NNZ;
}

// place: atomic-free, pos = row[dst] + rank
__global__ void place_k(const int* __restrict__ src, const int* __restrict__ dst,
                        const float* __restrict__ val, const int* __restrict__ rank,
                        const int* __restrict__ row, int2* __restrict__ sorted) {
    int e = blockIdx.x * blockDim.x + threadIdx.x;
    if (e >= NNZ) return;
    int d = dst[e];
    sorted[row[d] + rank[e]] = make_int2(src[e], __float_as_int(val[e]));
}

// ---------------- gather SpMM: Y[d] = sum val*X[src]; ACC += Y ---------------
__global__ void gather_k(const int* __restrict__ row, const int2* __restrict__ se,
                         const float* __restrict__ X, float* __restrict__ Y,
                         float* __restrict__ ACC) {
    int wid  = (blockIdx.x * blockDim.x + threadIdx.x) >> 6;   // node
    int lane = threadIdx.x & 63;                               // dim
    if (wid >= N_NODES) return;
    int beg = row[wid], end = row[wid + 1];
    float acc = 0.f;
    for (int base = beg; base < end; base += 64) {
        int rem = end - base;
        int n = rem < 64 ? rem : 64;
        int2 ev = make_int2(0, 0);
        if (lane < n) ev = se[base + lane];
        int n4 = (n + 3) & ~3;
        for (int j = 0; j < n4; j += 4) {
            int   s0 = __shfl(ev.x, j + 0, 64);
            int   s1 = __shfl(ev.x, j + 1, 64);
            int   s2 = __shfl(ev.x, j + 2, 64);
            int   s3 = __shfl(ev.x, j + 3, 64);
            float v0 = __int_as_float(__shfl(ev.y, j + 0, 64));
            float v1 = __int_as_float(__shfl(ev.y, j + 1, 64));
            float v2 = __int_as_float(__shfl(ev.y, j + 2, 64));
            float v3 = __int_as_float(__shfl(ev.y, j + 3, 64));
            float x0 = X[(s0 << 6) + lane];   // zero-padded lanes: v=0, s=0 (safe)
            float x1 = X[(s1 << 6) + lane];
            float x2 = X[(s2 << 6) + lane];
            float x3 = X[(s3 << 6) + lane];
            acc += v0 * x0;
            acc += v1 * x1;
            acc += v2 * x2;
            acc += v3 * x3;
        }
    }
    int o = (wid << 6) + lane;
    Y[o]   = acc;
    ACC[o] += acc;
}

// ---------------- final: gather rows, dot, sigmoid ---------------------------
__global__ void final_k(const int* __restrict__ users, const int* __restrict__ items,
                        const float* __restrict__ ACC, float* __restrict__ out) {
    int b    = blockIdx.x * (blockDim.x / 64) + (threadIdx.x / 64);
    int lane = threadIdx.x & 63;
    if (b >= BATCH) return;
    int ur = users[b];
    int ir = N_USERS + items[b];
    float u  = ACC[ur * 64 + lane];
    float it = ACC[ir * 64 + lane];
    float p  = u * it * (1.0f / 16.0f);
    #pragma unroll
    for (int off = 32; off; off >>= 1) p += __shfl_down(p, off, 64);
    if (lane == 0) out[b] = 1.0f / (1.0f + __expf(-p));
}

extern "C" void kernel_launch(void* const* d_in, const int* in_sizes, int n_in,
                              void* d_out, int out_size, void* d_ws, size_t ws_size,
                              hipStream_t stream) {
    const int*   users = (const int*)  d_in[0];
    const int*   items = (const int*)  d_in[1];
    const int*   esrc  = (const int*)  d_in[2];
    const int*   edst  = (const int*)  d_in[3];
    const float* eval  = (const float*)d_in[4];
    const float* uemb  = (const float*)d_in[5];
    const float* iemb  = (const float*)d_in[6];
    float*       out   = (float*)      d_out;

    const size_t EMB = (size_t)N_NODES * DIM * sizeof(float);      // 38.4 MB
    char* ws = (char*)d_ws;
    float* X      = (float*)(ws);
    float* Y      = (float*)(ws + EMB);
    float* ACC    = (float*)(ws + 2 * EMB);
    int2*  sorted = (int2*) (ws + 3 * EMB);                        // 32 MB
    char*  ws2    = ws + 3 * EMB + (size_t)NNZ * sizeof(int2);
    int*   row    = (int*)(ws2);                                   // N_NODES+1
    int*   cnt    = (int*)(ws2 + ((N_NODES + 2) * 4 + 255) / 256 * 256);
    int*   bsum   = (int*)((char*)cnt + ((size_t)N_NODES * 4 + 255) / 256 * 256);
    int*   rank   = (int*)(ws + EMB);   // aliases Y (dead until init_k)

    // ---- CSR build (by destination): rank + scan + atomic-free place ----
    hipMemsetAsync(cnt, 0, (size_t)N_NODES * 4, stream);
    rank_k<<<(NNZ + 255) / 256, 256, 0, stream>>>(edst, cnt, rank);
    const int NB = (N_NODES + 1023) / 1024;                        // 147
    scan1_k<<<NB, 256, 0, stream>>>(cnt, row, bsum);
    scan2_k<<<1, 256, 0, stream>>>(bsum, NB);
    scan3_k<<<(N_NODES + 255) / 256, 256, 0, stream>>>(row, bsum);
    place_k<<<(NNZ + 255) / 256, 256, 0, stream>>>(esrc, edst, eval, rank, row, sorted);

    // ---- init AFTER place (rank aliases Y) ----
    const int totv = N_NODES * DIM / 4;
    init_k<<<(totv + 255) / 256, 256, 0, stream>>>(
        (const float4*)uemb, (const float4*)iemb, (float4*)X, (float4*)ACC);

    // ---- 3 gather layers, ACC fused ----
    const int gthreads = N_NODES * 64;
    for (int l = 0; l < 3; ++l) {
        gather_k<<<(gthreads + 255) / 256, 256, 0, stream>>>(row, sorted, X, Y, ACC);
        float* tmp = X; X = Y; Y = tmp;
    }

    final_k<<<(BATCH * 64 + 255) / 256, 256, 0, stream>>>(users, items, ACC, out);
}

// Round 5
// 537.140 us; speedup vs baseline: 2.6838x; 1.2718x over previous
//
#include <hip/hip_runtime.h>
#include <hip/hip_bf16.h>

#define N_USERS 100000
#define N_ITEMS 50000
#define N_NODES 150000
#define DIM 64
#define NNZ 4000000
#define BATCH 4096
#define NCOPY 8

typedef __hip_bfloat16 bf16;

__device__ __forceinline__ float bf2f(bf16 h) { return __bfloat162float(h); }
__device__ __forceinline__ bf16  f2bf(float f) { return __float2bfloat16(f); }

// ---------------- conv: concat user/item embeddings into X0 (bf16) ----------
__global__ void conv_k(const float4* __restrict__ ue, const float4* __restrict__ ie,
                       ushort4* __restrict__ X0) {
    int i = blockIdx.x * blockDim.x + threadIdx.x;
    const int total  = N_NODES * DIM / 4;   // 2.4M float4
    const int ubound = N_USERS * DIM / 4;
    if (i >= total) return;
    float4 v = (i < ubound) ? ue[i] : ie[i - ubound];
    ushort4 o;
    bf16 a = f2bf(v.x), b = f2bf(v.y), c = f2bf(v.z), d = f2bf(v.w);
    o.x = *reinterpret_cast<ushort*>(&a);
    o.y = *reinterpret_cast<ushort*>(&b);
    o.z = *reinterpret_cast<ushort*>(&c);
    o.w = *reinterpret_cast<ushort*>(&d);
    X0[i] = o;
}

// ---------------- CSR build --------------------------------------------------
// rank8: XCD-local histogram copies (copy = blockIdx&7) + per-edge local rank
__global__ void rank8_k(const int* __restrict__ dst, int* __restrict__ cnt8,
                        ushort* __restrict__ rank) {
    int e = blockIdx.x * blockDim.x + threadIdx.x;
    if (e >= NNZ) return;
    int c = blockIdx.x & (NCOPY - 1);
    int r = atomicAdd(&cnt8[c * N_NODES + dst[e]], 1);
    rank[e] = (ushort)r;
}

// per-node exclusive prefix over the 8 copies (in place) + node total
__global__ void scanA_k(int* __restrict__ cnt8, int* __restrict__ tot) {
    int i = blockIdx.x * blockDim.x + threadIdx.x;
    if (i >= N_NODES) return;
    int s = 0;
    #pragma unroll
    for (int c = 0; c < NCOPY; ++c) {
        int v = cnt8[c * N_NODES + i];
        cnt8[c * N_NODES + i] = s;
        s += v;
    }
    tot[i] = s;
}

__global__ void scan1_k(const int* __restrict__ tot, int* __restrict__ row,
                        int* __restrict__ bsum) {
    __shared__ int sh[256];
    int tid  = threadIdx.x;
    int base = blockIdx.x * 1024 + tid * 4;
    int v0 = (base + 0 < N_NODES) ? tot[base + 0] : 0;
    int v1 = (base + 1 < N_NODES) ? tot[base + 1] : 0;
    int v2 = (base + 2 < N_NODES) ? tot[base + 2] : 0;
    int v3 = (base + 3 < N_NODES) ? tot[base + 3] : 0;
    int tsum = v0 + v1 + v2 + v3;
    sh[tid] = tsum;
    __syncthreads();
    for (int off = 1; off < 256; off <<= 1) {
        int t = (tid >= off) ? sh[tid - off] : 0;
        __syncthreads();
        sh[tid] += t;
        __syncthreads();
    }
    if (tid == 255) bsum[blockIdx.x] = sh[255];
    int excl = sh[tid] - tsum;
    if (base + 0 < N_NODES) row[base + 0] = excl;           excl += v0;
    if (base + 1 < N_NODES) row[base + 1] = excl;           excl += v1;
    if (base + 2 < N_NODES) row[base + 2] = excl;           excl += v2;
    if (base + 3 < N_NODES) row[base + 3] = excl;
}

__global__ void scan2_k(int* __restrict__ bsum, int nb) {
    __shared__ int sh[256];
    int tid = threadIdx.x;
    int v = (tid < nb) ? bsum[tid] : 0;
    sh[tid] = v;
    __syncthreads();
    for (int off = 1; off < 256; off <<= 1) {
        int t = (tid >= off) ? sh[tid - off] : 0;
        __syncthreads();
        sh[tid] += t;
        __syncthreads();
    }
    if (tid < nb) bsum[tid] = sh[tid] - v;
}

__global__ void scan3_k(int* __restrict__ row, const int* __restrict__ bsum) {
    int i = blockIdx.x * blockDim.x + threadIdx.x;
    if (i < N_NODES) row[i] += bsum[i >> 10];
    if (i == 0) row[N_NODES] = NNZ;
}

// place: atomic-free, pos = row[d] + copy_base[c][d] + rank
__global__ void place_k(const int* __restrict__ src, const int* __restrict__ dst,
                        const float* __restrict__ val, const ushort* __restrict__ rank,
                        const int* __restrict__ row, const int* __restrict__ off8,
                        int2* __restrict__ sorted) {
    int e = blockIdx.x * blockDim.x + threadIdx.x;
    if (e >= NNZ) return;
    int d = dst[e];
    int c = blockIdx.x & (NCOPY - 1);
    int pos = row[d] + off8[c * N_NODES + d] + (int)rank[e];
    sorted[pos] = make_int2(src[e], __float_as_int(val[e]));
}

// ---------------- gather SpMM (bf16 in/out): Y[d] = sum val*X[src] ----------
__global__ void gather16_k(const int* __restrict__ row, const int2* __restrict__ se,
                           const bf16* __restrict__ X, bf16* __restrict__ Y) {
    int wid  = (blockIdx.x * blockDim.x + threadIdx.x) >> 6;   // node
    int lane = threadIdx.x & 63;                               // dim
    if (wid >= N_NODES) return;
    int beg = row[wid], end = row[wid + 1];
    float acc = 0.f;
    for (int base = beg; base < end; base += 64) {
        int rem = end - base;
        int n = rem < 64 ? rem : 64;
        int2 ev = make_int2(0, 0);
        if (lane < n) ev = se[base + lane];
        int n4 = (n + 3) & ~3;
        for (int j = 0; j < n4; j += 4) {
            int   s0 = __shfl(ev.x, j + 0, 64);
            int   s1 = __shfl(ev.x, j + 1, 64);
            int   s2 = __shfl(ev.x, j + 2, 64);
            int   s3 = __shfl(ev.x, j + 3, 64);
            float v0 = __int_as_float(__shfl(ev.y, j + 0, 64));
            float v1 = __int_as_float(__shfl(ev.y, j + 1, 64));
            float v2 = __int_as_float(__shfl(ev.y, j + 2, 64));
            float v3 = __int_as_float(__shfl(ev.y, j + 3, 64));
            float x0 = bf2f(X[(s0 << 6) + lane]);   // padded lanes: v=0, s=0 (safe)
            float x1 = bf2f(X[(s1 << 6) + lane]);
            float x2 = bf2f(X[(s2 << 6) + lane]);
            float x3 = bf2f(X[(s3 << 6) + lane]);
            acc += v0 * x0;
            acc += v1 * x1;
            acc += v2 * x2;
            acc += v3 * x3;
        }
    }
    Y[(wid << 6) + lane] = f2bf(acc);
}

// ---------------- final: acc = (e0+x1+x2+x3)/4 for the 8192 rows, dot, sigmoid
__global__ void final_k(const int* __restrict__ users, const int* __restrict__ items,
                        const float* __restrict__ ue, const float* __restrict__ ie,
                        const bf16* __restrict__ X1, const bf16* __restrict__ X2,
                        const bf16* __restrict__ X3, float* __restrict__ out) {
    int b    = blockIdx.x * (blockDim.x / 64) + (threadIdx.x / 64);
    int lane = threadIdx.x & 63;
    if (b >= BATCH) return;
    int u  = users[b];
    int it = items[b];
    int uo = (u << 6) + lane;                       // user node == u
    int io = ((N_USERS + it) << 6) + lane;          // item node
    float au = ue[uo]               + bf2f(X1[uo]) + bf2f(X2[uo]) + bf2f(X3[uo]);
    float ai = ie[(it << 6) + lane] + bf2f(X1[io]) + bf2f(X2[io]) + bf2f(X3[io]);
    float p = au * ai * (1.0f / 16.0f);             // (/4 per side)
    #pragma unroll
    for (int off = 32; off; off >>= 1) p += __shfl_down(p, off, 64);
    if (lane == 0) out[b] = 1.0f / (1.0f + __expf(-p));
}

extern "C" void kernel_launch(void* const* d_in, const int* in_sizes, int n_in,
                              void* d_out, int out_size, void* d_ws, size_t ws_size,
                              hipStream_t stream) {
    const int*   users = (const int*)  d_in[0];
    const int*   items = (const int*)  d_in[1];
    const int*   esrc  = (const int*)  d_in[2];
    const int*   edst  = (const int*)  d_in[3];
    const float* eval  = (const float*)d_in[4];
    const float* uemb  = (const float*)d_in[5];
    const float* iemb  = (const float*)d_in[6];
    float*       out   = (float*)      d_out;

    const size_t XB = (size_t)N_NODES * DIM * sizeof(bf16);        // 19.2 MB
    char* ws = (char*)d_ws;
    bf16*   X0     = (bf16*)  (ws);
    bf16*   X1     = (bf16*)  (ws + XB);
    bf16*   X2     = (bf16*)  (ws + 2 * XB);
    bf16*   X3     = (bf16*)  (ws + 3 * XB);
    int2*   sorted = (int2*)  (ws + 4 * XB);                       // 32 MB
    char*   p      = ws + 4 * XB + (size_t)NNZ * sizeof(int2);
    ushort* rank   = (ushort*)(p);                p += (size_t)NNZ * 2;        // 8 MB
    int*    cnt8   = (int*)   (p);                p += (size_t)NCOPY * N_NODES * 4; // 4.8 MB
    int*    tot    = (int*)   (p);                p += ((size_t)N_NODES * 4 + 255) & ~255UL;
    int*    row    = (int*)   (p);                p += ((size_t)(N_NODES + 1) * 4 + 255) & ~255UL;
    int*    bsum   = (int*)   (p);

    // ---- CSR build (by destination) ----
    hipMemsetAsync(cnt8, 0, (size_t)NCOPY * N_NODES * 4, stream);
    rank8_k<<<(NNZ + 255) / 256, 256, 0, stream>>>(edst, cnt8, rank);
    scanA_k<<<(N_NODES + 255) / 256, 256, 0, stream>>>(cnt8, tot);
    const int NB = (N_NODES + 1023) / 1024;                        // 147
    scan1_k<<<NB, 256, 0, stream>>>(tot, row, bsum);
    scan2_k<<<1, 256, 0, stream>>>(bsum, NB);
    scan3_k<<<(N_NODES + 255) / 256, 256, 0, stream>>>(row, bsum);
    place_k<<<(NNZ + 255) / 256, 256, 0, stream>>>(esrc, edst, eval, rank, row,
                                                   cnt8, sorted);

    // ---- X0 = concat(uemb, iemb) in bf16 ----
    conv_k<<<(N_NODES * DIM / 4 + 255) / 256, 256, 0, stream>>>(
        (const float4*)uemb, (const float4*)iemb, (ushort4*)X0);

    // ---- 3 gather layers ----
    const int gthreads = N_NODES * 64;
    gather16_k<<<(gthreads + 255) / 256, 256, 0, stream>>>(row, sorted, X0, X1);
    gather16_k<<<(gthreads + 255) / 256, 256, 0, stream>>>(row, sorted, X1, X2);
    gather16_k<<<(gthreads + 255) / 256, 256, 0, stream>>>(row, sorted, X2, X3);

    final_k<<<(BATCH * 64 + 255) / 256, 256, 0, stream>>>(users, items, uemb, iemb,
                                                          X1, X2, X3, out);
}

// Round 6
// 437.193 us; speedup vs baseline: 3.2973x; 1.2286x over previous
//
#include <hip/hip_runtime.h>
#include <hip/hip_fp16.h>

#define N_USERS 100000
#define N_ITEMS 50000
#define N_NODES 150000
#define DIM 64
#define NNZ 4000000
#define BATCH 4096

#define NBUCK 586          // ceil(150000/256) buckets of 256 nodes
#define CAP   7680         // bucket capacity: mean 6827, sigma 82.5 -> +10.3 sigma
#define NB_C  256          // coarse blocks
#define CHUNK (NNZ / NB_C) // 15625

typedef __half f16;

__device__ __forceinline__ float h2f(f16 h) { return __half2float(h); }

// ---------------- gticket init: gticket[k] = k*CAP ---------------------------
__global__ void initt_k(int* __restrict__ gticket) {
    int i = blockIdx.x * blockDim.x + threadIdx.x;
    if (i < NBUCK) gticket[i] = i * CAP;
}

// ---------------- coarse: bucket edges by dst>>8 via LDS hist + block tickets
__global__ void coarse_k(const int* __restrict__ src, const int* __restrict__ dst,
                         const float* __restrict__ val, int* __restrict__ gticket,
                         int2* __restrict__ ev, unsigned char* __restrict__ dlo) {
    __shared__ int hist[NBUCK];
    __shared__ int base[NBUCK];
    __shared__ int tick[NBUCK];
    int t  = threadIdx.x;
    int lo = blockIdx.x * CHUNK;
    int hi = lo + CHUNK;           // NNZ divisible by NB_C
    for (int i = t; i < NBUCK; i += blockDim.x) hist[i] = 0;
    __syncthreads();
    for (int e = lo + t; e < hi; e += blockDim.x)
        atomicAdd(&hist[dst[e] >> 8], 1);
    __syncthreads();
    for (int i = t; i < NBUCK; i += blockDim.x) {
        base[i] = atomicAdd(&gticket[i], hist[i]);   // one agent atomic per (block,bucket)
        tick[i] = 0;
    }
    __syncthreads();
    for (int e = lo + t; e < hi; e += blockDim.x) {
        int d  = dst[e];
        int bk = d >> 8;
        int p  = base[bk] + atomicAdd(&tick[bk], 1); // LDS ticket
        ev[p]  = make_int2(src[e], __float_as_int(val[e]));
        dlo[p] = (unsigned char)(d & 255);
    }
}

// ---------------- scanC: bucket bases from final tickets ---------------------
__global__ void scanC_k(const int* __restrict__ gticket, int* __restrict__ bktbase) {
    __shared__ int sh[1024];
    int tid = threadIdx.x;
    int v = (tid < NBUCK) ? (gticket[tid] - tid * CAP) : 0;
    sh[tid] = v;
    __syncthreads();
    for (int off = 1; off < 1024; off <<= 1) {
        int t = (tid >= off) ? sh[tid - off] : 0;
        __syncthreads();
        sh[tid] += t;
        __syncthreads();
    }
    if (tid < NBUCK) bktbase[tid] = sh[tid] - v;   // exclusive
}

// ---------------- fine: per-bucket counting sort fully in LDS ----------------
__global__ void fine_k(const int* __restrict__ gticket, const int* __restrict__ bktbase,
                       const int2* __restrict__ ev, const unsigned char* __restrict__ dlo,
                       int2* __restrict__ sorted, int* __restrict__ row) {
    __shared__ int hist[256];
    __shared__ int sh[256];
    int k = blockIdx.x, t = threadIdx.x;
    hist[t] = 0;
    __syncthreads();
    int cnt = gticket[k] - k * CAP;
    int s0  = k * CAP;
    for (int i = t; i < cnt; i += 256)
        atomicAdd(&hist[dlo[s0 + i]], 1);
    __syncthreads();
    int v = hist[t];
    sh[t] = v;
    __syncthreads();
    for (int off = 1; off < 256; off <<= 1) {
        int tmp = (t >= off) ? sh[t - off] : 0;
        __syncthreads();
        sh[t] += tmp;
        __syncthreads();
    }
    int excl    = sh[t] - v;
    int rowbase = bktbase[k];
    int node    = (k << 8) + t;
    if (node < N_NODES) row[node] = rowbase + excl;
    if (k == 0 && t == 0) row[N_NODES] = NNZ;
    hist[t] = excl;                 // re-seed as ticket
    __syncthreads();
    for (int i = t; i < cnt; i += 256) {
        int p = atomicAdd(&hist[dlo[s0 + i]], 1);   // LDS ticket = local pos
        sorted[rowbase + p] = ev[s0 + i];
    }
}

// ---------------- conv: concat embeddings into X0 (fp16) ---------------------
__global__ void conv_k(const float4* __restrict__ ue, const float4* __restrict__ ie,
                       ushort4* __restrict__ X0) {
    int i = blockIdx.x * blockDim.x + threadIdx.x;
    const int total  = N_NODES * DIM / 4;
    const int ubound = N_USERS * DIM / 4;
    if (i >= total) return;
    float4 v = (i < ubound) ? ue[i] : ie[i - ubound];
    f16 a = __float2half(v.x), b = __float2half(v.y);
    f16 c = __float2half(v.z), d = __float2half(v.w);
    ushort4 o;
    o.x = *reinterpret_cast<ushort*>(&a);
    o.y = *reinterpret_cast<ushort*>(&b);
    o.z = *reinterpret_cast<ushort*>(&c);
    o.w = *reinterpret_cast<ushort*>(&d);
    X0[i] = o;
}

// ---------------- gather SpMM (fp16 in/out): Y[d] = sum val*X[src] ----------
__global__ void gather16_k(const int* __restrict__ row, const int2* __restrict__ se,
                           const f16* __restrict__ X, f16* __restrict__ Y) {
    int wid  = (blockIdx.x * blockDim.x + threadIdx.x) >> 6;   // node
    int lane = threadIdx.x & 63;                               // dim
    if (wid >= N_NODES) return;
    int beg = row[wid], end = row[wid + 1];
    float acc = 0.f;
    for (int base = beg; base < end; base += 64) {
        int rem = end - base;
        int n = rem < 64 ? rem : 64;
        int2 evv = make_int2(0, 0);
        if (lane < n) evv = se[base + lane];
        int n4 = (n + 3) & ~3;
        for (int j = 0; j < n4; j += 4) {
            int   s0 = __shfl(evv.x, j + 0, 64);
            int   s1 = __shfl(evv.x, j + 1, 64);
            int   s2 = __shfl(evv.x, j + 2, 64);
            int   s3 = __shfl(evv.x, j + 3, 64);
            float v0 = __int_as_float(__shfl(evv.y, j + 0, 64));
            float v1 = __int_as_float(__shfl(evv.y, j + 1, 64));
            float v2 = __int_as_float(__shfl(evv.y, j + 2, 64));
            float v3 = __int_as_float(__shfl(evv.y, j + 3, 64));
            float x0 = h2f(X[(s0 << 6) + lane]);   // padded lanes: v=0, s=0 (safe)
            float x1 = h2f(X[(s1 << 6) + lane]);
            float x2 = h2f(X[(s2 << 6) + lane]);
            float x3 = h2f(X[(s3 << 6) + lane]);
            acc += v0 * x0;
            acc += v1 * x1;
            acc += v2 * x2;
            acc += v3 * x3;
        }
    }
    Y[(wid << 6) + lane] = __float2half(acc);
}

// ---------------- final: acc = (e0+x1+x2+x3)/4 for gathered rows, dot, sigmoid
__global__ void final_k(const int* __restrict__ users, const int* __restrict__ items,
                        const float* __restrict__ ue, const float* __restrict__ ie,
                        const f16* __restrict__ X1, const f16* __restrict__ X2,
                        const f16* __restrict__ X3, float* __restrict__ out) {
    int b    = blockIdx.x * (blockDim.x / 64) + (threadIdx.x / 64);
    int lane = threadIdx.x & 63;
    if (b >= BATCH) return;
    int u  = users[b];
    int it = items[b];
    int uo = (u << 6) + lane;
    int io = ((N_USERS + it) << 6) + lane;
    float au = ue[uo]               + h2f(X1[uo]) + h2f(X2[uo]) + h2f(X3[uo]);
    float ai = ie[(it << 6) + lane] + h2f(X1[io]) + h2f(X2[io]) + h2f(X3[io]);
    float p = au * ai * (1.0f / 16.0f);
    #pragma unroll
    for (int off = 32; off; off >>= 1) p += __shfl_down(p, off, 64);
    if (lane == 0) out[b] = 1.0f / (1.0f + __expf(-p));
}

extern "C" void kernel_launch(void* const* d_in, const int* in_sizes, int n_in,
                              void* d_out, int out_size, void* d_ws, size_t ws_size,
                              hipStream_t stream) {
    const int*   users = (const int*)  d_in[0];
    const int*   items = (const int*)  d_in[1];
    const int*   esrc  = (const int*)  d_in[2];
    const int*   edst  = (const int*)  d_in[3];
    const float* eval  = (const float*)d_in[4];
    const float* uemb  = (const float*)d_in[5];
    const float* iemb  = (const float*)d_in[6];
    float*       out   = (float*)      d_out;

    const size_t XB = (size_t)N_NODES * DIM * sizeof(f16);         // 19.2 MB
    char* ws = (char*)d_ws;
    f16*  X0     = (f16*) (ws);
    f16*  X1     = (f16*) (ws + XB);
    f16*  X2     = (f16*) (ws + 2 * XB);
    f16*  X3     = (f16*) (ws + 3 * XB);
    int2* sorted = (int2*)(ws + 4 * XB);                           // 32 MB
    char* p      = ws + 4 * XB + (size_t)NNZ * sizeof(int2);
    int*  row     = (int*)(p);                 p += ((size_t)(N_NODES + 1) * 4 + 255) & ~255UL;
    int*  gticket = (int*)(p);                 p += (NBUCK * 4 + 255) & ~255UL;
    int*  bktbase = (int*)(p);
    // coarse staging aliases X0..X3 (dead until conv_k / gathers)
    int2*          cev  = (int2*)(ws);                             // 36.0 MB (over X0+X1)
    unsigned char* cdlo = (unsigned char*)(ws + 2 * XB);           // 4.5 MB (over X2)

    // ---- CSR build: LDS counting sort, no fabric atomics on hot path ----
    initt_k<<<(NBUCK + 255) / 256, 256, 0, stream>>>(gticket);
    coarse_k<<<NB_C, 512, 0, stream>>>(esrc, edst, eval, gticket, cev, cdlo);
    scanC_k<<<1, 1024, 0, stream>>>(gticket, bktbase);
    fine_k<<<NBUCK, 256, 0, stream>>>(gticket, bktbase, cev, cdlo, sorted, row);

    // ---- X0 = concat(uemb, iemb) in fp16 (coarse staging now dead) ----
    conv_k<<<(N_NODES * DIM / 4 + 255) / 256, 256, 0, stream>>>(
        (const float4*)uemb, (const float4*)iemb, (ushort4*)X0);

    // ---- 3 gather layers ----
    const int gthreads = N_NODES * 64;
    gather16_k<<<(gthreads + 255) / 256, 256, 0, stream>>>(row, sorted, X0, X1);
    gather16_k<<<(gthreads + 255) / 256, 256, 0, stream>>>(row, sorted, X1, X2);
    gather16_k<<<(gthreads + 255) / 256, 256, 0, stream>>>(row, sorted, X2, X3);

    final_k<<<(BATCH * 64 + 255) / 256, 256, 0, stream>>>(users, items, uemb, iemb,
                                                          X1, X2, X3, out);
}